// Round 8
// baseline (268.705 us; speedup 1.0000x reference)
//
#include <hip/hip_runtime.h>
#include <hip/hip_bf16.h>

using bf16 = __hip_bfloat16;
typedef __attribute__((ext_vector_type(8))) short bf16x8;   // 8 bf16 = 4 VGPR
typedef __attribute__((ext_vector_type(4))) float f32x4;    // MFMA C/D frag

#define DEVI __device__ __forceinline__

constexpr int Bn = 2, Sn = 2048, Dn = 2048, Hn = 16, DHn = 128;
constexpr int Mn = Bn * Sn;   // 4096

DEVI void gload_lds16(const bf16* g, bf16* l) {
  __builtin_amdgcn_global_load_lds(
      (__attribute__((address_space(1))) void*)g,
      (__attribute__((address_space(3))) void*)l,
      16, 0, 0);
}

// ---------------- f32 -> bf16 convert (vectorized 8/thread) ----------------
__global__ __launch_bounds__(256) void cvt_bf16_k(const float* __restrict__ in,
                                                  bf16* __restrict__ out, int n8) {
  int i = blockIdx.x * 256 + threadIdx.x;
  if (i >= n8) return;
  const float4* p = (const float4*)in + (size_t)i * 2;
  float4 a = p[0], b = p[1];
  union { bf16 h[8]; bf16x8 v; } u;
  u.h[0] = __float2bfloat16(a.x); u.h[1] = __float2bfloat16(a.y);
  u.h[2] = __float2bfloat16(a.z); u.h[3] = __float2bfloat16(a.w);
  u.h[4] = __float2bfloat16(b.x); u.h[5] = __float2bfloat16(b.y);
  u.h[6] = __float2bfloat16(b.z); u.h[7] = __float2bfloat16(b.w);
  *((bf16x8*)out + i) = u.v;
}

// ---------------- GEMM Z: C = A[M,K] * W[N,K]^T ----------------------------
// BM = MW*32 (MW m-frags/wave, 2 wm groups), BN=128, BK=32, 256 thr = 4
// waves (2M x 2N). Per-wave C = (MW*16) x 64. Single phase per K-tile:
//   { vmcnt(0); s_barrier; stage kt+1 -> slot^1; 12 ordered ds_reads;
//     setprio(1); MW*4 MFMA (compiler inserts counted lgkm ladder);
//     setprio(0) }
// One barrier/tile; vmcnt(0) waits loads issued a full tile (~4k cyc) ago.
// Slot^1 staging is safe: all waves' reads of slot^1 (tile kt-1) drained
// before they passed this tile's barrier. T2 XOR swizzle keeps conflicts 0.
template <int OUTF32, int NTOT, int NMAT, int MW>
__global__ __launch_bounds__(256, 2) void gemmZ(const bf16* __restrict__ A,
                                                const bf16* __restrict__ W,
                                                void* __restrict__ Cv) {
  constexpr int K = 2048, NT = K / 32;            // 64 K-tiles
  constexpr int BM = MW * 32;
  constexpr int SLOT = (BM + 128) * 32;           // elements per slot
  __shared__ bf16 smem[2 * SLOT];

  constexpr int MT = Mn / BM;
  const int nwg = NTOT * MT;
  const int orig = blockIdx.x;
  const int wgid = (orig & 7) * (nwg >> 3) + (orig >> 3);   // XCD swizzle (nwg%8==0)
  const int bm = wgid / NTOT;
  const int bnn = wgid % NTOT;
  constexpr int nper = NTOT / NMAT;
  const int z = bnn / nper;
  const int col0 = (bnn % nper) * 128;

  const int t = threadIdx.x;
  const int wave = t >> 6, lane = t & 63;
  const int wm = wave >> 1, wn = wave & 1;
  const int lr = lane & 15, lg = lane >> 4;
  const int rch = ((lg ^ ((lr >> 1) & 3)) * 8);       // swizzled read chunk
  const int srow = t >> 2;                            // staging row in unit
  const int sch = (t & 3) ^ ((t >> 3) & 3);           // pre-swizzled src chunk

  const bf16* Ab = A + (size_t)(bm * BM + srow) * K + sch * 8;
  const bf16* Bb = W + (size_t)z * (2048 * 2048) +
                   (size_t)(col0 + srow) * K + sch * 8;

  auto stgA = [&](int slot, int kt, int u) {
    gload_lds16(Ab + (size_t)u * 64 * K + kt * 32,
                smem + slot * SLOT + u * 2048 + t * 8);
  };
  auto stgB = [&](int slot, int kt, int v) {
    gload_lds16(Bb + (size_t)v * 64 * K + kt * 32,
                smem + slot * SLOT + BM * 32 + v * 2048 + t * 8);
  };

  f32x4 acc[MW][4];
  const f32x4 zf = {0.f, 0.f, 0.f, 0.f};
#pragma unroll
  for (int i = 0; i < MW; ++i)
#pragma unroll
    for (int j = 0; j < 4; ++j) acc[i][j] = zf;

  // prologue: stage tile 0 into slot 0
#pragma unroll
  for (int u = 0; u < MW / 2; ++u) stgA(0, 0, u);
  stgB(0, 0, 0); stgB(0, 0, 1);

#pragma unroll 2
  for (int kt = 0; kt < NT; ++kt) {
    const int slot = kt & 1;
    const bf16* sAb = smem + slot * SLOT;
    const bf16* sBb = sAb + BM * 32;

    asm volatile("s_waitcnt vmcnt(0)" ::: "memory");   // tile kt landed
    __builtin_amdgcn_sched_barrier(0);
    __builtin_amdgcn_s_barrier();                      // publish to all waves
    __builtin_amdgcn_sched_barrier(0);

    if (kt + 1 < NT) {                                 // prefetch next tile
#pragma unroll
      for (int u = 0; u < MW / 2; ++u) stgA(slot ^ 1, kt + 1, u);
      stgB(slot ^ 1, kt + 1, 0); stgB(slot ^ 1, kt + 1, 1);
    }

    bf16x8 bv[4], af[MW];
#pragma unroll
    for (int n = 0; n < 4; ++n)
      bv[n] = *(const bf16x8*)(sBb + (wn * 64 + n * 16 + lr) * 32 + rch);
#pragma unroll
    for (int i = 0; i < MW; ++i)
      af[i] = *(const bf16x8*)(sAb + (wm * (MW * 16) + i * 16 + lr) * 32 + rch);

    __builtin_amdgcn_s_setprio(1);
#pragma unroll
    for (int i = 0; i < MW; ++i)
#pragma unroll
      for (int n = 0; n < 4; ++n)
        acc[i][n] = __builtin_amdgcn_mfma_f32_16x16x32_bf16(af[i], bv[n], acc[i][n], 0, 0, 0);
    __builtin_amdgcn_s_setprio(0);
    __builtin_amdgcn_sched_barrier(0);   // nothing crosses into next tile
  }

  // epilogue
  const int r0 = bm * BM + wm * (MW * 16), c0 = col0 + wn * 64;
#pragma unroll
  for (int mm = 0; mm < MW; ++mm)
#pragma unroll
    for (int nn = 0; nn < 4; ++nn) {
      const int rr = r0 + mm * 16 + lg * 4;
      const int cc = c0 + nn * 16 + lr;
#pragma unroll
      for (int r = 0; r < 4; ++r) {
        float v = acc[mm][nn][r];
        if (OUTF32) {
          ((float*)Cv)[(size_t)(rr + r) * 2048 + cc] = v;
        } else {
          bf16* C = (bf16*)Cv + (size_t)z * (Mn * 2048);
          C[(size_t)(rr + r) * 2048 + cc] = __float2bfloat16(v);
        }
      }
    }
}

// ---------------- V transpose: per (b,h)  V[2048,128] -> VT[128,2048] ------
// (head = contiguous 128-row slab of the projection output, plain-view
//  semantics — do NOT treat head as a column group!)
__global__ __launch_bounds__(256, 2) void transpose_v(const bf16* __restrict__ V,
                                                      bf16* __restrict__ VT) {
  __shared__ bf16 tile[128 * 128];   // 32 KB, chunk-XOR-swizzled
  const int kt = blockIdx.x, bh = blockIdx.y;
  const bf16* Vh = V + (size_t)bh * (Sn * DHn);
  bf16* VTh = VT + (size_t)bh * (DHn * Sn);
  const int t = threadIdx.x;
  const int rr = t >> 4, cc = t & 15;
#pragma unroll
  for (int i = 0; i < 8; ++i) {
    int r = rr + i * 16;
    int ch = cc ^ ((r >> 3) & 7);
    *(bf16x8*)(tile + r * 128 + ch * 8) =
        *(const bf16x8*)(Vh + (size_t)(kt * 128 + r) * DHn + cc * 8);
  }
  __syncthreads();
  const int dr = t >> 4, li = t & 15;
#pragma unroll
  for (int i = 0; i < 8; ++i) {
    int dh = dr + i * 16;
    union { bf16 h[8]; bf16x8 v; } u;
#pragma unroll
    for (int j = 0; j < 8; ++j) {
      int k = li * 8 + j;
      int ch = (dh >> 3) ^ ((k >> 3) & 7);
      u.h[j] = tile[k * 128 + ch * 8 + (dh & 7)];
    }
    *(bf16x8*)(VTh + (size_t)dh * Sn + kt * 128 + li * 8) = u.v;
  }
}

// ---------------- causal flash attention v3 --------------------------------
// QBLK=128, 8 waves x 16 q-rows, KBLK=64. Block pairs qb=j with qb=15-j
// (34 tiles each, perfectly balanced; grid 8 x 32 = 256 = 1/CU).
// 2-phase double-buffered K/VT staging via global_load_lds + XOR swizzle.
__global__ __launch_bounds__(512, 1) void attn_k3(const bf16* __restrict__ Q,
                                                  const bf16* __restrict__ K,
                                                  const bf16* __restrict__ VT,
                                                  bf16* __restrict__ Mg) {
  __shared__ bf16 smem[40960];         // 80 KB
  bf16* sK0 = smem;                    // [64][128] swizzled (16 KB)
  bf16* sK1 = smem + 8192;
  bf16* sV0 = smem + 16384;            // [128][64] swizzled (16 KB)
  bf16* sV1 = smem + 24576;
  bf16* sP  = smem + 32768;            // 8 waves x [16][64] swizzled (16 KB)
  bf16* sO  = smem;                    // epilogue reuse [128][128] (32 KB)

  const int j = blockIdx.x;            // pair index 0..7
  const int bh = blockIdx.y;
  const bf16* Qh = Q + (size_t)bh * (Sn * DHn);
  const bf16* Kh = K + (size_t)bh * (Sn * DHn);
  const bf16* VTh = VT + (size_t)bh * (DHn * Sn);
  const int b = bh >> 4, h = bh & 15;

  const int t = threadIdx.x, wave = t >> 6, lane = t & 63;
  const int lr = lane & 15, lg = lane >> 4;

  auto STAGE = [&](int buf, int kt) {
    bf16* dK = buf ? sK1 : sK0;
    bf16* dV = buf ? sV1 : sV0;
#pragma unroll
    for (int i = 0; i < 2; ++i) {
      int c = i * 512 + t;               // 0..1023
      int row = c >> 4, c16 = c & 15;
      gload_lds16(Kh + (size_t)(kt * 64 + row) * DHn + ((c16 ^ (row & 7)) * 8),
                  dK + c * 8);
    }
#pragma unroll
    for (int i = 0; i < 2; ++i) {
      int c = i * 512 + t;
      int row = c >> 3, c8 = c & 7;
      gload_lds16(VTh + (size_t)row * Sn + kt * 64 + ((c8 ^ (row & 7)) * 8),
                  dV + c * 8);
    }
  };

  const f32x4 zf = {0.f, 0.f, 0.f, 0.f};

  for (int pi = 0; pi < 2; ++pi) {
    const int qb = pi ? (15 - j) : j;    // QBLK=128 block index
    const int nt = qb * 2 + 2;
    const int q0 = qb * 128 + wave * 16;

    bf16x8 qf[4];
#pragma unroll
    for (int kk = 0; kk < 4; ++kk)
      qf[kk] = *(const bf16x8*)(Qh + (size_t)(q0 + lr) * DHn + kk * 32 + lg * 8);

    f32x4 o[8];
#pragma unroll
    for (int d = 0; d < 8; ++d) o[d] = zf;
    float mrun[4], lrun[4];
#pragma unroll
    for (int r = 0; r < 4; ++r) { mrun[r] = -3e38f; lrun[r] = 0.f; }

    STAGE(0, 0);
    __syncthreads();   // drains vmcnt(0): buf0 ready
    int cur = 0;

    for (int kt = 0; kt < nt; ++kt) {
      if (kt + 1 < nt) STAGE(cur ^ 1, kt + 1);   // prefetch in flight over compute

      bf16* sKc = cur ? sK1 : sK0;
      bf16* sVc = cur ? sV1 : sV0;

      // S = Q K^T
      f32x4 sfr[4];
#pragma unroll
      for (int nn = 0; nn < 4; ++nn) sfr[nn] = zf;
#pragma unroll
      for (int kk = 0; kk < 4; ++kk)
#pragma unroll
        for (int nn = 0; nn < 4; ++nn) {
          int row = nn * 16 + lr;
          int ch = (kk * 4 + lg) ^ (row & 7);
          bf16x8 kf = *(const bf16x8*)(sKc + row * DHn + ch * 8);
          sfr[nn] = __builtin_amdgcn_mfma_f32_16x16x32_bf16(qf[kk], kf, sfr[nn], 0, 0, 0);
        }

      // online softmax (rows: lg*4+r, cols: nn*16+lr)
      const bool maskt = (kt >= qb * 2);
      float pv[4][4];
#pragma unroll
      for (int nn = 0; nn < 4; ++nn)
#pragma unroll
        for (int r = 0; r < 4; ++r) {
          float v = sfr[nn][r] * (1.0f / 128.0f);
          if (maskt) {
            int kg = kt * 64 + nn * 16 + lr;
            int qg = q0 + lg * 4 + r;
            if (kg > qg) v = -1e30f;
          }
          pv[nn][r] = v;
        }
      float mnew[4], alpha[4], rsum[4];
#pragma unroll
      for (int r = 0; r < 4; ++r) {
        float rm = fmaxf(fmaxf(pv[0][r], pv[1][r]), fmaxf(pv[2][r], pv[3][r]));
        rm = fmaxf(rm, __shfl_xor(rm, 1));
        rm = fmaxf(rm, __shfl_xor(rm, 2));
        rm = fmaxf(rm, __shfl_xor(rm, 4));
        rm = fmaxf(rm, __shfl_xor(rm, 8));
        mnew[r] = fmaxf(mrun[r], rm);
        alpha[r] = __expf(mrun[r] - mnew[r]);
        mrun[r] = mnew[r];
        rsum[r] = 0.f;
      }
#pragma unroll
      for (int nn = 0; nn < 4; ++nn)
#pragma unroll
        for (int r = 0; r < 4; ++r) {
          float p = __expf(pv[nn][r] - mnew[r]);
          pv[nn][r] = p;
          rsum[r] += p;
        }
#pragma unroll
      for (int r = 0; r < 4; ++r) {
        float s = rsum[r];
        s += __shfl_xor(s, 1); s += __shfl_xor(s, 2);
        s += __shfl_xor(s, 4); s += __shfl_xor(s, 8);
        lrun[r] = lrun[r] * alpha[r] + s;
      }
#pragma unroll
      for (int d = 0; d < 8; ++d)
#pragma unroll
        for (int r = 0; r < 4; ++r) o[d][r] *= alpha[r];

      // P -> LDS (swizzled), per-wave [16][64] region
#pragma unroll
      for (int nn = 0; nn < 4; ++nn)
#pragma unroll
        for (int r = 0; r < 4; ++r) {
          int row = lg * 4 + r;
          int chk = (nn * 2 + (lr >> 3)) ^ (row & 7);
          sP[wave * 1024 + row * 64 + chk * 8 + (lr & 7)] = __float2bfloat16(pv[nn][r]);
        }

      // O += P V
      bf16x8 pf[2];
#pragma unroll
      for (int kk = 0; kk < 2; ++kk) {
        int ch = (kk * 4 + lg) ^ (lr & 7);
        pf[kk] = *(const bf16x8*)(sP + wave * 1024 + lr * 64 + ch * 8);
      }
#pragma unroll
      for (int d = 0; d < 8; ++d)
#pragma unroll
        for (int kk = 0; kk < 2; ++kk) {
          int vrow = d * 16 + lr;
          int vch = (kk * 4 + lg) ^ (vrow & 7);
          bf16x8 vf = *(const bf16x8*)(sVc + vrow * 64 + vch * 8);
          o[d] = __builtin_amdgcn_mfma_f32_16x16x32_bf16(pf[kk], vf, o[d], 0, 0, 0);
        }

      __syncthreads();   // drains prefetch vmcnt + all ds reads of cur
      cur ^= 1;
    }

    // epilogue: normalize, stage to LDS (swizzled), coalesced global write
    float inv[4];
#pragma unroll
    for (int r = 0; r < 4; ++r) inv[r] = 1.0f / lrun[r];
#pragma unroll
    for (int d = 0; d < 8; ++d)
#pragma unroll
      for (int r = 0; r < 4; ++r) {
        int row = wave * 16 + lg * 4 + r;
        int col = d * 16 + lr;
        int chk = ((col >> 3) ^ (row & 7));
        sO[row * 128 + chk * 8 + (col & 7)] = __float2bfloat16(o[d][r] * inv[r]);
      }
    __syncthreads();
    bf16* Mh = Mg + ((size_t)(b * Sn + qb * 128)) * Dn + h * DHn;
#pragma unroll
    for (int i = 0; i < 4; ++i) {
      int row = (t >> 4) + i * 32;
      int c16 = t & 15;
      *(bf16x8*)(Mh + (size_t)row * Dn + c16 * 8) =
          *(const bf16x8*)(sO + row * 128 + ((c16 ^ (row & 7)) * 8));
    }
    __syncthreads();   // sO region is re-staged by next pass
  }
}

// ---------------------------------------------------------------------------
extern "C" void kernel_launch(void* const* d_in, const int* in_sizes, int n_in,
                              void* d_out, int out_size, void* d_ws, size_t ws_size,
                              hipStream_t stream) {
  const float* x = (const float*)d_in[0];
  const float* Wq = (const float*)d_in[1];
  const float* Wk = (const float*)d_in[2];
  const float* Wv = (const float*)d_in[3];
  const float* Wo = (const float*)d_in[4];
  float* out = (float*)d_out;

  char* ws = (char*)d_ws;
  bf16* xb = (bf16*)ws;            ws += (size_t)Mn * Dn * 2;        // 16 MB
  bf16* Wb = (bf16*)ws;            ws += (size_t)4 * Dn * Dn * 2;    // 32 MB (q,k,v,o)
  bf16* QKV = (bf16*)ws;           ws += (size_t)3 * Mn * Dn * 2;    // 48 MB
  bf16* VT = (bf16*)ws;            ws += (size_t)Bn * Hn * DHn * Sn * 2; // 16 MB
  bf16* Mg = (bf16*)ws;            ws += (size_t)Mn * Dn * 2;        // 16 MB

  const int nx8 = Mn * Dn / 8;     // 1048576
  const int nw8 = Dn * Dn / 8;     // 524288
  cvt_bf16_k<<<nx8 / 256, 256, 0, stream>>>(x, xb, nx8);
  cvt_bf16_k<<<nw8 / 256, 256, 0, stream>>>(Wq, Wb + 0 * (size_t)Dn * Dn, nw8);
  cvt_bf16_k<<<nw8 / 256, 256, 0, stream>>>(Wk, Wb + 1 * (size_t)Dn * Dn, nw8);
  cvt_bf16_k<<<nw8 / 256, 256, 0, stream>>>(Wv, Wb + 2 * (size_t)Dn * Dn, nw8);
  cvt_bf16_k<<<nw8 / 256, 256, 0, stream>>>(Wo, Wb + 3 * (size_t)Dn * Dn, nw8);

  // Q,K,V = x @ W{q,k,v}^T -> bf16 (768 blocks, BM=256)
  gemmZ<0, 48, 3, 8><<<768, 256, 0, stream>>>(xb, Wb, (void*)QKV);

  // per-head V transpose (plain-view head slabs)
  transpose_v<<<dim3(16, 32), 256, 0, stream>>>(QKV + 2 * (size_t)Mn * Dn, VT);

  // causal attention -> merged [4096, 2048] bf16
  attn_k3<<<dim3(8, 32), 512, 0, stream>>>(QKV, QKV + (size_t)Mn * Dn, VT, Mg);

  // out = merged @ Wo^T -> f32 (BM=128 -> 512 blocks = 2/CU)
  gemmZ<1, 16, 1, 4><<<512, 256, 0, stream>>>(Mg, Wb + 3 * (size_t)Dn * Dn, (void*)out);
}

// Round 9
// 258.501 us; speedup vs baseline: 1.0395x; 1.0395x over previous
//
#include <hip/hip_runtime.h>
#include <hip/hip_bf16.h>

using bf16 = __hip_bfloat16;
typedef __attribute__((ext_vector_type(8))) short bf16x8;   // 8 bf16 = 4 VGPR
typedef __attribute__((ext_vector_type(4))) float f32x4;    // MFMA C/D frag

#define DEVI __device__ __forceinline__

constexpr int Bn = 2, Sn = 2048, Dn = 2048, Hn = 16, DHn = 128;
constexpr int Mn = Bn * Sn;   // 4096

DEVI void gload_lds16(const bf16* g, bf16* l) {
  __builtin_amdgcn_global_load_lds(
      (__attribute__((address_space(1))) void*)g,
      (__attribute__((address_space(3))) void*)l,
      16, 0, 0);
}

// ---------------- fused f32 -> bf16 convert (x + 4 weights, one launch) ----
__global__ __launch_bounds__(256) void cvt_all_k(const float* __restrict__ x,
                                                 const float* __restrict__ wq,
                                                 const float* __restrict__ wk,
                                                 const float* __restrict__ wv,
                                                 const float* __restrict__ wo,
                                                 bf16* __restrict__ xb,
                                                 bf16* __restrict__ wb) {
  const int which = blockIdx.y;
  const float* src;
  bf16* dst;
  int n8;
  if (which == 0) { src = x;  dst = xb; n8 = Mn * Dn / 8; }
  else {
    src = (which == 1) ? wq : (which == 2) ? wk : (which == 3) ? wv : wo;
    dst = wb + (size_t)(which - 1) * Dn * Dn;
    n8 = Dn * Dn / 8;
  }
  for (int i = blockIdx.x * 256 + threadIdx.x; i < n8; i += gridDim.x * 256) {
    const float4* p = (const float4*)src + (size_t)i * 2;
    float4 a = p[0], b = p[1];
    union { bf16 h[8]; bf16x8 v; } u;
    u.h[0] = __float2bfloat16(a.x); u.h[1] = __float2bfloat16(a.y);
    u.h[2] = __float2bfloat16(a.z); u.h[3] = __float2bfloat16(a.w);
    u.h[4] = __float2bfloat16(b.x); u.h[5] = __float2bfloat16(b.y);
    u.h[6] = __float2bfloat16(b.z); u.h[7] = __float2bfloat16(b.w);
    *((bf16x8*)dst + i) = u.v;
  }
}

// ---------------- GEMM 3S: C = A[M,K] * W[N,K]^T ---------------------------
// BM = MW*32, BN=128, BK=32, 256 thr = 4 waves (2M x 2N), per-wave C =
// (MW*16) x 64. THREE-slot LDS ring, depth-2 counted pipeline, ONE barrier
// per K-tile:
//   tile kt: { vmcnt(VW) [retire kt, keep kt+1 in flight]; s_barrier;
//              stage kt+2 -> slot (kt+2)%3; 12 ds_reads of slot kt%3;
//              setprio(1); MW*4 MFMA (compiler lgkm ladder); setprio(0) }
// Slot-reuse safety: slot (kt+2)%3 was last read at tile kt-1; every wave's
// tile-(kt-1) ds_reads complete before their consuming MFMAs issue, hence
// before the wave passes tile kt's barrier. VW = per-wave loads/tile.
template <int OUTF32, int NTOT, int NMAT, int MW>
__global__ __launch_bounds__(256, 2) void gemm3s(const bf16* __restrict__ A,
                                                 const bf16* __restrict__ W,
                                                 void* __restrict__ Cv) {
  constexpr int K = 2048, NT = K / 32;            // 64 K-tiles
  constexpr int BM = MW * 32;
  constexpr int SLOT = (BM + 128) * 32;           // elements per slot
  __shared__ bf16 smem[3 * SLOT];

  constexpr int MT = Mn / BM;
  const int nwg = NTOT * MT;
  const int orig = blockIdx.x;
  const int wgid = (orig & 7) * (nwg >> 3) + (orig >> 3);   // XCD swizzle (nwg%8==0)
  const int bm = wgid / NTOT;
  const int bnn = wgid % NTOT;
  constexpr int nper = NTOT / NMAT;
  const int z = bnn / nper;
  const int col0 = (bnn % nper) * 128;

  const int t = threadIdx.x;
  const int wave = t >> 6, lane = t & 63;
  const int wm = wave >> 1, wn = wave & 1;
  const int lr = lane & 15, lg = lane >> 4;
  const int rch = ((lg ^ ((lr >> 1) & 3)) * 8);       // swizzled read chunk
  const int srow = t >> 2;                            // staging row in unit
  const int sch = (t & 3) ^ ((t >> 3) & 3);           // pre-swizzled src chunk

  const bf16* Ab = A + (size_t)(bm * BM + srow) * K + sch * 8;
  const bf16* Bb = W + (size_t)z * (2048 * 2048) +
                   (size_t)(col0 + srow) * K + sch * 8;

  auto stgA = [&](int slot, int kt, int u) {
    gload_lds16(Ab + (size_t)u * 64 * K + kt * 32,
                smem + slot * SLOT + u * 2048 + t * 8);
  };
  auto stgB = [&](int slot, int kt, int v) {
    gload_lds16(Bb + (size_t)v * 64 * K + kt * 32,
                smem + slot * SLOT + BM * 32 + v * 2048 + t * 8);
  };
  auto stage_tile = [&](int slot, int kt) {
#pragma unroll
    for (int u = 0; u < MW / 2; ++u) stgA(slot, kt, u);
    stgB(slot, kt, 0); stgB(slot, kt, 1);
  };

  f32x4 acc[MW][4];
  const f32x4 zf = {0.f, 0.f, 0.f, 0.f};
#pragma unroll
  for (int i = 0; i < MW; ++i)
#pragma unroll
    for (int j = 0; j < 4; ++j) acc[i][j] = zf;

  // prologue: tiles 0,1 into slots 0,1
  stage_tile(0, 0);
  stage_tile(1, 1);

  int slot = 0;
#pragma unroll 1
  for (int kt = 0; kt < NT; ++kt) {
    const bf16* sAb = smem + slot * SLOT;
    const bf16* sBb = sAb + BM * 32;

    // retire tile kt's loads; keep tile kt+1's VW loads in flight
    if (kt == NT - 1)            asm volatile("s_waitcnt vmcnt(0)" ::: "memory");
    else if constexpr (MW == 8)  asm volatile("s_waitcnt vmcnt(6)" ::: "memory");
    else                         asm volatile("s_waitcnt vmcnt(4)" ::: "memory");
    __builtin_amdgcn_s_barrier();                      // publish slot kt

    if (kt + 2 < NT) {                                 // depth-2 prefetch
      int ps = slot + 2; if (ps >= 3) ps -= 3;
      stage_tile(ps, kt + 2);
    }

    bf16x8 bv[4], af[MW];
#pragma unroll
    for (int n = 0; n < 4; ++n)
      bv[n] = *(const bf16x8*)(sBb + (wn * 64 + n * 16 + lr) * 32 + rch);
#pragma unroll
    for (int i = 0; i < MW; ++i)
      af[i] = *(const bf16x8*)(sAb + (wm * (MW * 16) + i * 16 + lr) * 32 + rch);

    __builtin_amdgcn_s_setprio(1);
#pragma unroll
    for (int i = 0; i < MW; ++i)
#pragma unroll
      for (int n = 0; n < 4; ++n)
        acc[i][n] = __builtin_amdgcn_mfma_f32_16x16x32_bf16(af[i], bv[n], acc[i][n], 0, 0, 0);
    __builtin_amdgcn_s_setprio(0);

    slot = (slot == 2) ? 0 : slot + 1;
  }

  // epilogue
  const int r0 = bm * BM + wm * (MW * 16), c0 = col0 + wn * 64;
#pragma unroll
  for (int mm = 0; mm < MW; ++mm)
#pragma unroll
    for (int nn = 0; nn < 4; ++nn) {
      const int rr = r0 + mm * 16 + lg * 4;
      const int cc = c0 + nn * 16 + lr;
#pragma unroll
      for (int r = 0; r < 4; ++r) {
        float v = acc[mm][nn][r];
        if (OUTF32) {
          ((float*)Cv)[(size_t)(rr + r) * 2048 + cc] = v;
        } else {
          bf16* C = (bf16*)Cv + (size_t)z * (Mn * 2048);
          C[(size_t)(rr + r) * 2048 + cc] = __float2bfloat16(v);
        }
      }
    }
}

// ---------------- V transpose: per (b,h)  V[2048,128] -> VT[128,2048] ------
// (head = contiguous 128-row slab of the projection output, plain-view
//  semantics — do NOT treat head as a column group!)
__global__ __launch_bounds__(256, 2) void transpose_v(const bf16* __restrict__ V,
                                                      bf16* __restrict__ VT) {
  __shared__ bf16 tile[128 * 128];   // 32 KB, chunk-XOR-swizzled
  const int kt = blockIdx.x, bh = blockIdx.y;
  const bf16* Vh = V + (size_t)bh * (Sn * DHn);
  bf16* VTh = VT + (size_t)bh * (DHn * Sn);
  const int t = threadIdx.x;
  const int rr = t >> 4, cc = t & 15;
#pragma unroll
  for (int i = 0; i < 8; ++i) {
    int r = rr + i * 16;
    int ch = cc ^ ((r >> 3) & 7);
    *(bf16x8*)(tile + r * 128 + ch * 8) =
        *(const bf16x8*)(Vh + (size_t)(kt * 128 + r) * DHn + cc * 8);
  }
  __syncthreads();
  const int dr = t >> 4, li = t & 15;
#pragma unroll
  for (int i = 0; i < 8; ++i) {
    int dh = dr + i * 16;
    union { bf16 h[8]; bf16x8 v; } u;
#pragma unroll
    for (int j = 0; j < 8; ++j) {
      int k = li * 8 + j;
      int ch = (dh >> 3) ^ ((k >> 3) & 7);
      u.h[j] = tile[k * 128 + ch * 8 + (dh & 7)];
    }
    *(bf16x8*)(VTh + (size_t)dh * Sn + kt * 128 + li * 8) = u.v;
  }
}

// ---------------- causal flash attention v3 --------------------------------
// QBLK=128, 8 waves x 16 q-rows, KBLK=64. Block pairs qb=j with qb=15-j
// (34 tiles each, perfectly balanced; grid 8 x 32 = 256 = 1/CU).
// 2-phase double-buffered K/VT staging via global_load_lds + XOR swizzle.
__global__ __launch_bounds__(512, 1) void attn_k3(const bf16* __restrict__ Q,
                                                  const bf16* __restrict__ K,
                                                  const bf16* __restrict__ VT,
                                                  bf16* __restrict__ Mg) {
  __shared__ bf16 smem[40960];         // 80 KB
  bf16* sK0 = smem;                    // [64][128] swizzled (16 KB)
  bf16* sK1 = smem + 8192;
  bf16* sV0 = smem + 16384;            // [128][64] swizzled (16 KB)
  bf16* sV1 = smem + 24576;
  bf16* sP  = smem + 32768;            // 8 waves x [16][64] swizzled (16 KB)
  bf16* sO  = smem;                    // epilogue reuse [128][128] (32 KB)

  const int j = blockIdx.x;            // pair index 0..7
  const int bh = blockIdx.y;
  const bf16* Qh = Q + (size_t)bh * (Sn * DHn);
  const bf16* Kh = K + (size_t)bh * (Sn * DHn);
  const bf16* VTh = VT + (size_t)bh * (DHn * Sn);
  const int b = bh >> 4, h = bh & 15;

  const int t = threadIdx.x, wave = t >> 6, lane = t & 63;
  const int lr = lane & 15, lg = lane >> 4;

  auto STAGE = [&](int buf, int kt) {
    bf16* dK = buf ? sK1 : sK0;
    bf16* dV = buf ? sV1 : sV0;
#pragma unroll
    for (int i = 0; i < 2; ++i) {
      int c = i * 512 + t;               // 0..1023
      int row = c >> 4, c16 = c & 15;
      gload_lds16(Kh + (size_t)(kt * 64 + row) * DHn + ((c16 ^ (row & 7)) * 8),
                  dK + c * 8);
    }
#pragma unroll
    for (int i = 0; i < 2; ++i) {
      int c = i * 512 + t;
      int row = c >> 3, c8 = c & 7;
      gload_lds16(VTh + (size_t)row * Sn + kt * 64 + ((c8 ^ (row & 7)) * 8),
                  dV + c * 8);
    }
  };

  const f32x4 zf = {0.f, 0.f, 0.f, 0.f};

  for (int pi = 0; pi < 2; ++pi) {
    const int qb = pi ? (15 - j) : j;    // QBLK=128 block index
    const int nt = qb * 2 + 2;
    const int q0 = qb * 128 + wave * 16;

    bf16x8 qf[4];
#pragma unroll
    for (int kk = 0; kk < 4; ++kk)
      qf[kk] = *(const bf16x8*)(Qh + (size_t)(q0 + lr) * DHn + kk * 32 + lg * 8);

    f32x4 o[8];
#pragma unroll
    for (int d = 0; d < 8; ++d) o[d] = zf;
    float mrun[4], lrun[4];
#pragma unroll
    for (int r = 0; r < 4; ++r) { mrun[r] = -3e38f; lrun[r] = 0.f; }

    STAGE(0, 0);
    __syncthreads();   // drains vmcnt(0): buf0 ready
    int cur = 0;

    for (int kt = 0; kt < nt; ++kt) {
      if (kt + 1 < nt) STAGE(cur ^ 1, kt + 1);   // prefetch in flight over compute

      bf16* sKc = cur ? sK1 : sK0;
      bf16* sVc = cur ? sV1 : sV0;

      // S = Q K^T
      f32x4 sfr[4];
#pragma unroll
      for (int nn = 0; nn < 4; ++nn) sfr[nn] = zf;
#pragma unroll
      for (int kk = 0; kk < 4; ++kk)
#pragma unroll
        for (int nn = 0; nn < 4; ++nn) {
          int row = nn * 16 + lr;
          int ch = (kk * 4 + lg) ^ (row & 7);
          bf16x8 kf = *(const bf16x8*)(sKc + row * DHn + ch * 8);
          sfr[nn] = __builtin_amdgcn_mfma_f32_16x16x32_bf16(qf[kk], kf, sfr[nn], 0, 0, 0);
        }

      // online softmax (rows: lg*4+r, cols: nn*16+lr)
      const bool maskt = (kt >= qb * 2);
      float pv[4][4];
#pragma unroll
      for (int nn = 0; nn < 4; ++nn)
#pragma unroll
        for (int r = 0; r < 4; ++r) {
          float v = sfr[nn][r] * (1.0f / 128.0f);
          if (maskt) {
            int kg = kt * 64 + nn * 16 + lr;
            int qg = q0 + lg * 4 + r;
            if (kg > qg) v = -1e30f;
          }
          pv[nn][r] = v;
        }
      float mnew[4], alpha[4], rsum[4];
#pragma unroll
      for (int r = 0; r < 4; ++r) {
        float rm = fmaxf(fmaxf(pv[0][r], pv[1][r]), fmaxf(pv[2][r], pv[3][r]));
        rm = fmaxf(rm, __shfl_xor(rm, 1));
        rm = fmaxf(rm, __shfl_xor(rm, 2));
        rm = fmaxf(rm, __shfl_xor(rm, 4));
        rm = fmaxf(rm, __shfl_xor(rm, 8));
        mnew[r] = fmaxf(mrun[r], rm);
        alpha[r] = __expf(mrun[r] - mnew[r]);
        mrun[r] = mnew[r];
        rsum[r] = 0.f;
      }
#pragma unroll
      for (int nn = 0; nn < 4; ++nn)
#pragma unroll
        for (int r = 0; r < 4; ++r) {
          float p = __expf(pv[nn][r] - mnew[r]);
          pv[nn][r] = p;
          rsum[r] += p;
        }
#pragma unroll
      for (int r = 0; r < 4; ++r) {
        float s = rsum[r];
        s += __shfl_xor(s, 1); s += __shfl_xor(s, 2);
        s += __shfl_xor(s, 4); s += __shfl_xor(s, 8);
        lrun[r] = lrun[r] * alpha[r] + s;
      }
#pragma unroll
      for (int d = 0; d < 8; ++d)
#pragma unroll
        for (int r = 0; r < 4; ++r) o[d][r] *= alpha[r];

      // P -> LDS (swizzled), per-wave [16][64] region
#pragma unroll
      for (int nn = 0; nn < 4; ++nn)
#pragma unroll
        for (int r = 0; r < 4; ++r) {
          int row = lg * 4 + r;
          int chk = (nn * 2 + (lr >> 3)) ^ (row & 7);
          sP[wave * 1024 + row * 64 + chk * 8 + (lr & 7)] = __float2bfloat16(pv[nn][r]);
        }

      // O += P V
      bf16x8 pf[2];
#pragma unroll
      for (int kk = 0; kk < 2; ++kk) {
        int ch = (kk * 4 + lg) ^ (lr & 7);
        pf[kk] = *(const bf16x8*)(sP + wave * 1024 + lr * 64 + ch * 8);
      }
#pragma unroll
      for (int d = 0; d < 8; ++d)
#pragma unroll
        for (int kk = 0; kk < 2; ++kk) {
          int vrow = d * 16 + lr;
          int vch = (kk * 4 + lg) ^ (vrow & 7);
          bf16x8 vf = *(const bf16x8*)(sVc + vrow * 64 + vch * 8);
          o[d] = __builtin_amdgcn_mfma_f32_16x16x32_bf16(pf[kk], vf, o[d], 0, 0, 0);
        }

      __syncthreads();   // drains prefetch vmcnt + all ds reads of cur
      cur ^= 1;
    }

    // epilogue: normalize, stage to LDS (swizzled), coalesced global write
    float inv[4];
#pragma unroll
    for (int r = 0; r < 4; ++r) inv[r] = 1.0f / lrun[r];
#pragma unroll
    for (int d = 0; d < 8; ++d)
#pragma unroll
      for (int r = 0; r < 4; ++r) {
        int row = wave * 16 + lg * 4 + r;
        int col = d * 16 + lr;
        int chk = ((col >> 3) ^ (row & 7));
        sO[row * 128 + chk * 8 + (col & 7)] = __float2bfloat16(o[d][r] * inv[r]);
      }
    __syncthreads();
    bf16* Mh = Mg + ((size_t)(b * Sn + qb * 128)) * Dn + h * DHn;
#pragma unroll
    for (int i = 0; i < 4; ++i) {
      int row = (t >> 4) + i * 32;
      int c16 = t & 15;
      *(bf16x8*)(Mh + (size_t)row * Dn + c16 * 8) =
          *(const bf16x8*)(sO + row * 128 + ((c16 ^ (row & 7)) * 8));
    }
    __syncthreads();   // sO region is re-staged by next pass
  }
}

// ---------------------------------------------------------------------------
extern "C" void kernel_launch(void* const* d_in, const int* in_sizes, int n_in,
                              void* d_out, int out_size, void* d_ws, size_t ws_size,
                              hipStream_t stream) {
  const float* x = (const float*)d_in[0];
  const float* Wq = (const float*)d_in[1];
  const float* Wk = (const float*)d_in[2];
  const float* Wv = (const float*)d_in[3];
  const float* Wo = (const float*)d_in[4];
  float* out = (float*)d_out;

  char* ws = (char*)d_ws;
  bf16* xb = (bf16*)ws;            ws += (size_t)Mn * Dn * 2;        // 16 MB
  bf16* Wb = (bf16*)ws;            ws += (size_t)4 * Dn * Dn * 2;    // 32 MB (q,k,v,o)
  bf16* QKV = (bf16*)ws;           ws += (size_t)3 * Mn * Dn * 2;    // 48 MB
  bf16* VT = (bf16*)ws;            ws += (size_t)Bn * Hn * DHn * Sn * 2; // 16 MB
  bf16* Mg = (bf16*)ws;            ws += (size_t)Mn * Dn * 2;        // 16 MB

  // all f32->bf16 conversions in one launch
  cvt_all_k<<<dim3(2048, 5), 256, 0, stream>>>(x, Wq, Wk, Wv, Wo, xb, Wb);

  // Q,K,V = x @ W{q,k,v}^T -> bf16 (768 blocks, BM=256)
  gemm3s<0, 48, 3, 8><<<768, 256, 0, stream>>>(xb, Wb, (void*)QKV);

  // per-head V transpose (plain-view head slabs)
  transpose_v<<<dim3(16, 32), 256, 0, stream>>>(QKV + 2 * (size_t)Mn * Dn, VT);

  // causal attention -> merged [4096, 2048] bf16
  attn_k3<<<dim3(8, 32), 512, 0, stream>>>(QKV, QKV + (size_t)Mn * Dn, VT, Mg);

  // out = merged @ Wo^T -> f32 (BM=128 -> 512 blocks)
  gemm3s<1, 16, 1, 4><<<512, 256, 0, stream>>>(Mg, Wb + 3 * (size_t)Dn * Dn, (void*)out);
}

// Round 10
// 257.013 us; speedup vs baseline: 1.0455x; 1.0058x over previous
//
#include <hip/hip_runtime.h>
#include <hip/hip_bf16.h>

using bf16 = __hip_bfloat16;
typedef __attribute__((ext_vector_type(8))) short bf16x8;   // 8 bf16 = 4 VGPR
typedef __attribute__((ext_vector_type(4))) float f32x4;    // MFMA C/D frag

#define DEVI __device__ __forceinline__

constexpr int Bn = 2, Sn = 2048, Dn = 2048, Hn = 16, DHn = 128;
constexpr int Mn = Bn * Sn;   // 4096

DEVI void gload_lds16(const bf16* g, bf16* l) {
  __builtin_amdgcn_global_load_lds(
      (__attribute__((address_space(1))) void*)g,
      (__attribute__((address_space(3))) void*)l,
      16, 0, 0);
}

// ---------------- fused f32 -> bf16 convert (x + 4 weights, one launch) ----
__global__ __launch_bounds__(256) void cvt_all_k(const float* __restrict__ x,
                                                 const float* __restrict__ wq,
                                                 const float* __restrict__ wk,
                                                 const float* __restrict__ wv,
                                                 const float* __restrict__ wo,
                                                 bf16* __restrict__ xb,
                                                 bf16* __restrict__ wb) {
  const int which = blockIdx.y;
  const float* src;
  bf16* dst;
  int n8;
  if (which == 0) { src = x;  dst = xb; n8 = Mn * Dn / 8; }
  else {
    src = (which == 1) ? wq : (which == 2) ? wk : (which == 3) ? wv : wo;
    dst = wb + (size_t)(which - 1) * Dn * Dn;
    n8 = Dn * Dn / 8;
  }
  for (int i = blockIdx.x * 256 + threadIdx.x; i < n8; i += gridDim.x * 256) {
    const float4* p = (const float4*)src + (size_t)i * 2;
    float4 a = p[0], b = p[1];
    union { bf16 h[8]; bf16x8 v; } u;
    u.h[0] = __float2bfloat16(a.x); u.h[1] = __float2bfloat16(a.y);
    u.h[2] = __float2bfloat16(a.z); u.h[3] = __float2bfloat16(a.w);
    u.h[4] = __float2bfloat16(b.x); u.h[5] = __float2bfloat16(b.y);
    u.h[6] = __float2bfloat16(b.z); u.h[7] = __float2bfloat16(b.w);
    *((bf16x8*)dst + i) = u.v;
  }
}

// ---------------- GEMM 8F: fine-phase (m201-style) C = A[M,K] * W[N,K]^T ---
// BM=128, BN=256, BK=64, 512 thr = 8 waves (2M x 4N), per-wave C = 64x64
// (acc[4][4]); 16 MFMA per phase, 2 phases (kk=0/1) per K-tile.
// 3-slot LDS ring (144 KB, 1 block/CU), depth-2 counted pipeline:
//   tile top:  { vmcnt(6) [retire kt's 6 loads; kt+1's stay in flight];
//                s_barrier }                       // slot kt published
//   phase kk:  { 8 ds_read_b128 (swizzled); stage 3 units of kt+2;
//                s_barrier; lgkmcnt(0); sched_barrier(0);
//                setprio(1); 16 MFMA; setprio(0); s_barrier* }
//   (*ph1's trailing barrier is the next tile-top barrier)
// Slot safety: slot (kt+2)%3's last readers ran at tile kt-1; every wave
// drains those ds_reads (lgkmcnt(0)) before its tile-(kt-1) ph1 MFMA, hence
// before passing tile kt's top barrier. Staging into it at tile kt is safe.
// T2 swizzle: LDS row-major [rows][64], chunk16 c' = c ^ (row&7); linear
// gload_lds dest + pre-swizzled global source (involution).
template <int OUTF32, int NCT, int NMAT>
__global__ __launch_bounds__(512, 1) void gemm8f(const bf16* __restrict__ A,
                                                 const bf16* __restrict__ W,
                                                 void* __restrict__ Cv) {
  constexpr int K = 2048, NT = K / 64;            // 32 K-tiles
  constexpr int SLOTE = (128 + 256) * 64;         // 24576 elems per slot
  __shared__ bf16 smem[3 * SLOTE];                // 147456 B

  constexpr int MT = Mn / 128;                    // 32 row tiles
  const int nwg = MT * NCT;
  const int orig = blockIdx.x;
  const int wgid = (orig & 7) * (nwg >> 3) + (orig >> 3);   // XCD swizzle (nwg%8==0)
  const int bm = wgid / NCT;                      // bcn fastest -> A-panel L2 reuse
  const int bcn = wgid % NCT;
  constexpr int nper = NCT / NMAT;
  const int z = bcn / nper;
  const int col0 = (bcn % nper) * 256;

  const int t = threadIdx.x;
  const int wave = t >> 6, lane = t & 63;
  const int wm = wave >> 2, wn = wave & 3;
  const int lr = lane & 15, lg = lane >> 4;
  const int swz = lr & 7;

  // staging: unit = 8 KB = 64 rows x 128 B; thread t -> row t>>3, chunk t&7,
  // global source chunk pre-swizzled by row&7.
  const int srow = t >> 3;
  const int schk = (t & 7) ^ (srow & 7);
  const bf16* Ab = A + (size_t)(bm * 128 + srow) * K + schk * 8;
  const bf16* Bb = W + (size_t)z * (2048 * 2048) +
                   (size_t)(col0 + srow) * K + schk * 8;

  auto stgA = [&](int slot, int kt, int u) {
    gload_lds16(Ab + (size_t)u * 64 * K + kt * 64,
                smem + slot * SLOTE + u * 4096 + t * 8);
  };
  auto stgB = [&](int slot, int kt, int u) {
    gload_lds16(Bb + (size_t)u * 64 * K + kt * 64,
                smem + slot * SLOTE + 8192 + u * 4096 + t * 8);
  };

  f32x4 acc[4][4];
  const f32x4 zf = {0.f, 0.f, 0.f, 0.f};
#pragma unroll
  for (int i = 0; i < 4; ++i)
#pragma unroll
    for (int j = 0; j < 4; ++j) acc[i][j] = zf;

  // prologue: tiles 0,1 -> slots 0,1 (per-thread FIFO: t0's 6, then t1's 6)
  stgA(0, 0, 0); stgA(0, 0, 1);
  stgB(0, 0, 0); stgB(0, 0, 1); stgB(0, 0, 2); stgB(0, 0, 3);
  stgA(1, 1, 0); stgA(1, 1, 1);
  stgB(1, 1, 0); stgB(1, 1, 1); stgB(1, 1, 2); stgB(1, 1, 3);

  int sl = 0;
#pragma unroll 1
  for (int kt = 0; kt < NT; ++kt) {
    const bf16* sA = smem + sl * SLOTE;
    const bf16* sB = sA + 8192;
    int sl2 = sl + 2; if (sl2 >= 3) sl2 -= 3;
    const bool pf = (kt + 2 < NT);

    // ---- tile top: publish slot kt ----
    if (kt == NT - 1) asm volatile("s_waitcnt vmcnt(0)" ::: "memory");
    else              asm volatile("s_waitcnt vmcnt(6)" ::: "memory");
    __builtin_amdgcn_s_barrier();

    // ---- phase 0 (kk=0) ----
    {
      bf16x8 af[4], bv[4];
#pragma unroll
      for (int i = 0; i < 4; ++i)
        af[i] = *(const bf16x8*)(sA + (wm * 64 + i * 16 + lr) * 64 + ((lg ^ swz) * 8));
#pragma unroll
      for (int n = 0; n < 4; ++n)
        bv[n] = *(const bf16x8*)(sB + (wn * 64 + n * 16 + lr) * 64 + ((lg ^ swz) * 8));
      if (pf) { stgA(sl2, kt + 2, 0); stgA(sl2, kt + 2, 1); stgB(sl2, kt + 2, 0); }
      __builtin_amdgcn_s_barrier();
      asm volatile("s_waitcnt lgkmcnt(0)" ::: "memory");
      __builtin_amdgcn_sched_barrier(0);
      __builtin_amdgcn_s_setprio(1);
#pragma unroll
      for (int i = 0; i < 4; ++i)
#pragma unroll
        for (int n = 0; n < 4; ++n)
          acc[i][n] = __builtin_amdgcn_mfma_f32_16x16x32_bf16(af[i], bv[n], acc[i][n], 0, 0, 0);
      __builtin_amdgcn_s_setprio(0);
      __builtin_amdgcn_s_barrier();
    }

    // ---- phase 1 (kk=1) ----
    {
      bf16x8 af[4], bv[4];
#pragma unroll
      for (int i = 0; i < 4; ++i)
        af[i] = *(const bf16x8*)(sA + (wm * 64 + i * 16 + lr) * 64 + (((4 + lg) ^ swz) * 8));
#pragma unroll
      for (int n = 0; n < 4; ++n)
        bv[n] = *(const bf16x8*)(sB + (wn * 64 + n * 16 + lr) * 64 + (((4 + lg) ^ swz) * 8));
      if (pf) { stgB(sl2, kt + 2, 1); stgB(sl2, kt + 2, 2); stgB(sl2, kt + 2, 3); }
      __builtin_amdgcn_s_barrier();
      asm volatile("s_waitcnt lgkmcnt(0)" ::: "memory");
      __builtin_amdgcn_sched_barrier(0);
      __builtin_amdgcn_s_setprio(1);
#pragma unroll
      for (int i = 0; i < 4; ++i)
#pragma unroll
        for (int n = 0; n < 4; ++n)
          acc[i][n] = __builtin_amdgcn_mfma_f32_16x16x32_bf16(af[i], bv[n], acc[i][n], 0, 0, 0);
      __builtin_amdgcn_s_setprio(0);
      // trailing barrier = next tile's top barrier
    }

    sl = (sl == 2) ? 0 : sl + 1;
  }

  // epilogue
  const int r0 = bm * 128 + wm * 64, c0 = col0 + wn * 64;
#pragma unroll
  for (int mm = 0; mm < 4; ++mm)
#pragma unroll
    for (int nn = 0; nn < 4; ++nn) {
      const int rr = r0 + mm * 16 + lg * 4;
      const int cc = c0 + nn * 16 + lr;
#pragma unroll
      for (int r = 0; r < 4; ++r) {
        float v = acc[mm][nn][r];
        if (OUTF32) {
          ((float*)Cv)[(size_t)(rr + r) * 2048 + cc] = v;
        } else {
          bf16* C = (bf16*)Cv + (size_t)z * (Mn * 2048);
          C[(size_t)(rr + r) * 2048 + cc] = __float2bfloat16(v);
        }
      }
    }
}

// ---------------- V transpose: per (b,h)  V[2048,128] -> VT[128,2048] ------
// (head = contiguous 128-row slab of the projection output, plain-view
//  semantics — do NOT treat head as a column group!)
__global__ __launch_bounds__(256, 2) void transpose_v(const bf16* __restrict__ V,
                                                      bf16* __restrict__ VT) {
  __shared__ bf16 tile[128 * 128];   // 32 KB, chunk-XOR-swizzled
  const int kt = blockIdx.x, bh = blockIdx.y;
  const bf16* Vh = V + (size_t)bh * (Sn * DHn);
  bf16* VTh = VT + (size_t)bh * (DHn * Sn);
  const int t = threadIdx.x;
  const int rr = t >> 4, cc = t & 15;
#pragma unroll
  for (int i = 0; i < 8; ++i) {
    int r = rr + i * 16;
    int ch = cc ^ ((r >> 3) & 7);
    *(bf16x8*)(tile + r * 128 + ch * 8) =
        *(const bf16x8*)(Vh + (size_t)(kt * 128 + r) * DHn + cc * 8);
  }
  __syncthreads();
  const int dr = t >> 4, li = t & 15;
#pragma unroll
  for (int i = 0; i < 8; ++i) {
    int dh = dr + i * 16;
    union { bf16 h[8]; bf16x8 v; } u;
#pragma unroll
    for (int j = 0; j < 8; ++j) {
      int k = li * 8 + j;
      int ch = (dh >> 3) ^ ((k >> 3) & 7);
      u.h[j] = tile[k * 128 + ch * 8 + (dh & 7)];
    }
    *(bf16x8*)(VTh + (size_t)dh * Sn + kt * 128 + li * 8) = u.v;
  }
}

// ---------------- causal flash attention v3 --------------------------------
// QBLK=128, 8 waves x 16 q-rows, KBLK=64. Block pairs qb=j with qb=15-j
// (34 tiles each, perfectly balanced; 256 blocks = 1/CU). 1D grid decode
// groups the 8 same-bh blocks onto one XCD (K/V L2 reuse).
__global__ __launch_bounds__(512, 1) void attn_k3(const bf16* __restrict__ Q,
                                                  const bf16* __restrict__ K,
                                                  const bf16* __restrict__ VT,
                                                  bf16* __restrict__ Mg) {
  __shared__ bf16 smem[40960];         // 80 KB
  bf16* sK0 = smem;                    // [64][128] swizzled (16 KB)
  bf16* sK1 = smem + 8192;
  bf16* sV0 = smem + 16384;            // [128][64] swizzled (16 KB)
  bf16* sV1 = smem + 24576;
  bf16* sP  = smem + 32768;            // 8 waves x [16][64] swizzled (16 KB)
  bf16* sO  = smem;                    // epilogue reuse [128][128] (32 KB)

  const int bi = blockIdx.x;           // XCD-grouped decode
  const int xcd = bi & 7, slt = bi >> 3;
  const int bh = (slt & 3) * 8 + xcd;  // all 8 j-blocks of bh share an XCD
  const int j = slt >> 2;              // pair index 0..7
  const bf16* Qh = Q + (size_t)bh * (Sn * DHn);
  const bf16* Kh = K + (size_t)bh * (Sn * DHn);
  const bf16* VTh = VT + (size_t)bh * (DHn * Sn);
  const int b = bh >> 4, h = bh & 15;

  const int t = threadIdx.x, wave = t >> 6, lane = t & 63;
  const int lr = lane & 15, lg = lane >> 4;

  auto STAGE = [&](int buf, int kt) {
    bf16* dK = buf ? sK1 : sK0;
    bf16* dV = buf ? sV1 : sV0;
#pragma unroll
    for (int i = 0; i < 2; ++i) {
      int c = i * 512 + t;               // 0..1023
      int row = c >> 4, c16 = c & 15;
      gload_lds16(Kh + (size_t)(kt * 64 + row) * DHn + ((c16 ^ (row & 7)) * 8),
                  dK + c * 8);
    }
#pragma unroll
    for (int i = 0; i < 2; ++i) {
      int c = i * 512 + t;
      int row = c >> 3, c8 = c & 7;
      gload_lds16(VTh + (size_t)row * Sn + kt * 64 + ((c8 ^ (row & 7)) * 8),
                  dV + c * 8);
    }
  };

  const f32x4 zf = {0.f, 0.f, 0.f, 0.f};

  for (int pi = 0; pi < 2; ++pi) {
    const int qb = pi ? (15 - j) : j;    // QBLK=128 block index
    const int nt = qb * 2 + 2;
    const int q0 = qb * 128 + wave * 16;

    bf16x8 qf[4];
#pragma unroll
    for (int kk = 0; kk < 4; ++kk)
      qf[kk] = *(const bf16x8*)(Qh + (size_t)(q0 + lr) * DHn + kk * 32 + lg * 8);

    f32x4 o[8];
#pragma unroll
    for (int d = 0; d < 8; ++d) o[d] = zf;
    float mrun[4], lrun[4];
#pragma unroll
    for (int r = 0; r < 4; ++r) { mrun[r] = -3e38f; lrun[r] = 0.f; }

    STAGE(0, 0);
    __syncthreads();   // drains vmcnt(0): buf0 ready
    int cur = 0;

    for (int kt = 0; kt < nt; ++kt) {
      if (kt + 1 < nt) STAGE(cur ^ 1, kt + 1);   // prefetch in flight over compute

      bf16* sKc = cur ? sK1 : sK0;
      bf16* sVc = cur ? sV1 : sV0;

      // S = Q K^T
      f32x4 sfr[4];
#pragma unroll
      for (int nn = 0; nn < 4; ++nn) sfr[nn] = zf;
#pragma unroll
      for (int kk = 0; kk < 4; ++kk)
#pragma unroll
        for (int nn = 0; nn < 4; ++nn) {
          int row = nn * 16 + lr;
          int ch = (kk * 4 + lg) ^ (row & 7);
          bf16x8 kf = *(const bf16x8*)(sKc + row * DHn + ch * 8);
          sfr[nn] = __builtin_amdgcn_mfma_f32_16x16x32_bf16(qf[kk], kf, sfr[nn], 0, 0, 0);
        }

      // online softmax (rows: lg*4+r, cols: nn*16+lr)
      const bool maskt = (kt >= qb * 2);
      float pv[4][4];
#pragma unroll
      for (int nn = 0; nn < 4; ++nn)
#pragma unroll
        for (int r = 0; r < 4; ++r) {
          float v = sfr[nn][r] * (1.0f / 128.0f);
          if (maskt) {
            int kg = kt * 64 + nn * 16 + lr;
            int qg = q0 + lg * 4 + r;
            if (kg > qg) v = -1e30f;
          }
          pv[nn][r] = v;
        }
      float mnew[4], alpha[4], rsum[4];
#pragma unroll
      for (int r = 0; r < 4; ++r) {
        float rm = fmaxf(fmaxf(pv[0][r], pv[1][r]), fmaxf(pv[2][r], pv[3][r]));
        rm = fmaxf(rm, __shfl_xor(rm, 1));
        rm = fmaxf(rm, __shfl_xor(rm, 2));
        rm = fmaxf(rm, __shfl_xor(rm, 4));
        rm = fmaxf(rm, __shfl_xor(rm, 8));
        mnew[r] = fmaxf(mrun[r], rm);
        alpha[r] = __expf(mrun[r] - mnew[r]);
        mrun[r] = mnew[r];
        rsum[r] = 0.f;
      }
#pragma unroll
      for (int nn = 0; nn < 4; ++nn)
#pragma unroll
        for (int r = 0; r < 4; ++r) {
          float p = __expf(pv[nn][r] - mnew[r]);
          pv[nn][r] = p;
          rsum[r] += p;
        }
#pragma unroll
      for (int r = 0; r < 4; ++r) {
        float s = rsum[r];
        s += __shfl_xor(s, 1); s += __shfl_xor(s, 2);
        s += __shfl_xor(s, 4); s += __shfl_xor(s, 8);
        lrun[r] = lrun[r] * alpha[r] + s;
      }
#pragma unroll
      for (int d = 0; d < 8; ++d)
#pragma unroll
        for (int r = 0; r < 4; ++r) o[d][r] *= alpha[r];

      // P -> LDS (swizzled), per-wave [16][64] region
#pragma unroll
      for (int nn = 0; nn < 4; ++nn)
#pragma unroll
        for (int r = 0; r < 4; ++r) {
          int row = lg * 4 + r;
          int chk = (nn * 2 + (lr >> 3)) ^ (row & 7);
          sP[wave * 1024 + row * 64 + chk * 8 + (lr & 7)] = __float2bfloat16(pv[nn][r]);
        }

      // O += P V
      bf16x8 pf[2];
#pragma unroll
      for (int kk = 0; kk < 2; ++kk) {
        int ch = (kk * 4 + lg) ^ (lr & 7);
        pf[kk] = *(const bf16x8*)(sP + wave * 1024 + lr * 64 + ch * 8);
      }
#pragma unroll
      for (int d = 0; d < 8; ++d)
#pragma unroll
        for (int kk = 0; kk < 2; ++kk) {
          int vrow = d * 16 + lr;
          int vch = (kk * 4 + lg) ^ (vrow & 7);
          bf16x8 vf = *(const bf16x8*)(sVc + vrow * 64 + vch * 8);
          o[d] = __builtin_amdgcn_mfma_f32_16x16x32_bf16(pf[kk], vf, o[d], 0, 0, 0);
        }

      __syncthreads();   // drains prefetch vmcnt + all ds reads of cur
      cur ^= 1;
    }

    // epilogue: normalize, stage to LDS (swizzled), coalesced global write
    float inv[4];
#pragma unroll
    for (int r = 0; r < 4; ++r) inv[r] = 1.0f / lrun[r];
#pragma unroll
    for (int d = 0; d < 8; ++d)
#pragma unroll
      for (int r = 0; r < 4; ++r) {
        int row = wave * 16 + lg * 4 + r;
        int col = d * 16 + lr;
        int chk = ((col >> 3) ^ (row & 7));
        sO[row * 128 + chk * 8 + (col & 7)] = __float2bfloat16(o[d][r] * inv[r]);
      }
    __syncthreads();
    bf16* Mh = Mg + ((size_t)(b * Sn + qb * 128)) * Dn + h * DHn;
#pragma unroll
    for (int i = 0; i < 4; ++i) {
      int row = (t >> 4) + i * 32;
      int c16 = t & 15;
      *(bf16x8*)(Mh + (size_t)row * Dn + c16 * 8) =
          *(const bf16x8*)(sO + row * 128 + ((c16 ^ (row & 7)) * 8));
    }
    __syncthreads();   // sO region is re-staged by next pass
  }
}

// ---------------------------------------------------------------------------
extern "C" void kernel_launch(void* const* d_in, const int* in_sizes, int n_in,
                              void* d_out, int out_size, void* d_ws, size_t ws_size,
                              hipStream_t stream) {
  const float* x = (const float*)d_in[0];
  const float* Wq = (const float*)d_in[1];
  const float* Wk = (const float*)d_in[2];
  const float* Wv = (const float*)d_in[3];
  const float* Wo = (const float*)d_in[4];
  float* out = (float*)d_out;

  char* ws = (char*)d_ws;
  bf16* xb = (bf16*)ws;            ws += (size_t)Mn * Dn * 2;        // 16 MB
  bf16* Wb = (bf16*)ws;            ws += (size_t)4 * Dn * Dn * 2;    // 32 MB (q,k,v,o)
  bf16* QKV = (bf16*)ws;           ws += (size_t)3 * Mn * Dn * 2;    // 48 MB
  bf16* VT = (bf16*)ws;            ws += (size_t)Bn * Hn * DHn * Sn * 2; // 16 MB
  bf16* Mg = (bf16*)ws;            ws += (size_t)Mn * Dn * 2;        // 16 MB

  // all f32->bf16 conversions in one launch
  cvt_all_k<<<dim3(2048, 5), 256, 0, stream>>>(x, Wq, Wk, Wv, Wo, xb, Wb);

  // Q,K,V = x @ W{q,k,v}^T -> bf16 (32 x 24 = 768 blocks = 3 exact rounds)
  gemm8f<0, 24, 3><<<768, 512, 0, stream>>>(xb, Wb, (void*)QKV);

  // per-head V transpose (plain-view head slabs)
  transpose_v<<<dim3(16, 32), 256, 0, stream>>>(QKV + 2 * (size_t)Mn * Dn, VT);

  // causal attention -> merged [4096, 2048] bf16 (XCD-grouped grid)
  attn_k3<<<256, 512, 0, stream>>>(QKV, QKV + (size_t)Mn * Dn, VT, Mg);

  // out = merged @ Wo^T -> f32 (32 x 8 = 256 blocks = 1 exact round)
  gemm8f<1, 8, 1><<<256, 512, 0, stream>>>(Mg, Wb + 3 * (size_t)Dn * Dn, (void*)out);
}